// Round 6
// baseline (2062.472 us; speedup 1.0000x reference)
//
#include <hip/hip_runtime.h>
#include <hip/hip_fp16.h>

#define HID 1024
#define QCOLS 512
#define KP 2048   // physical K per operand: [hi(1024) | lo(1024)]
#define NT 48     // logical K' = 3072 = 48 tiles of 64

typedef _Float16 f16x8 __attribute__((ext_vector_type(8)));
typedef float f32x4 __attribute__((ext_vector_type(4)));

// ---- K0: transpose+convert+split both weights in one dispatch ----------------
__global__ void tconv_both(const float* __restrict__ w2, __half* __restrict__ w2t,
                           const float* __restrict__ w3, __half* __restrict__ w3t) {
  __shared__ float tile[32][33];
  const int z = blockIdx.z;
  const int N = z ? QCOLS : HID;
  if (blockIdx.x * 32 >= N) return;
  const float* src = z ? w3 : w2;
  __half* dst = z ? w3t : w2t;
  int n0 = blockIdx.x * 32, k0 = blockIdx.y * 32;
  int tx = threadIdx.x, ty = threadIdx.y;
  for (int i = ty; i < 32; i += 8)
    tile[i][tx] = src[(size_t)(k0 + i) * N + n0 + tx];
  __syncthreads();
  for (int i = ty; i < 32; i += 8) {
    float v = tile[tx][i] * 256.f;
    __half h = __float2half(v);
    size_t o = (size_t)(n0 + i) * KP + k0 + tx;
    dst[o] = h;
    dst[o + 1024] = __float2half(v - __half2float(h));
  }
}

// ---- K1: h1 = relu(yA @ w1 + b1) fp32, split to [hi|lo] f16 (x64) ------------
__global__ __launch_bounds__(256)
void h1k(const float* __restrict__ y, const float* __restrict__ w1,
         const float* __restrict__ b1, __half* __restrict__ h1,
         int row0, int nrows) {
  const int t = threadIdx.x & 127;
  const int rl = threadIdx.x >> 7;
  const long r = (long)blockIdx.x * 2 + rl;
  if (r >= nrows) return;
  const float* yr = y + (size_t)(row0 + r) * 17;
  float yv[8];
#pragma unroll
  for (int k = 0; k < 8; ++k) yv[k] = yr[k];
  const int c0 = t * 8;
  f32x4 a0 = *(const f32x4*)(b1 + c0);
  f32x4 a1 = *(const f32x4*)(b1 + c0 + 4);
#pragma unroll
  for (int k = 0; k < 8; ++k) {
    const f32x4 w0 = *(const f32x4*)(w1 + k * HID + c0);
    const f32x4 w1v = *(const f32x4*)(w1 + k * HID + c0 + 4);
#pragma unroll
    for (int j = 0; j < 4; ++j) {
      a0[j] = fmaf(yv[k], w0[j], a0[j]);
      a1[j] = fmaf(yv[k], w1v[j], a1[j]);
    }
  }
  f16x8 hi, lo;
#pragma unroll
  for (int j = 0; j < 8; ++j) {
    float v = fmaxf(j < 4 ? a0[j] : a1[j - 4], 0.f) * 64.f;
    _Float16 h = (_Float16)v;
    hi[j] = h;
    lo[j] = (_Float16)(v - (float)h);
  }
  *(f16x8*)(h1 + (size_t)r * KP + c0) = hi;
  *(f16x8*)(h1 + (size_t)r * KP + c0 + 1024) = lo;
}

// ---- K2: 256x256 deep-pipelined split-f16 GEMM, relu -> split f16 ------------
__global__ __launch_bounds__(512, 2)
void g2relu(const __half* __restrict__ A, const __half* __restrict__ B,
            const float* __restrict__ bias, __half* __restrict__ Co) {
  __shared__ char lds[131072];
  const int tid = threadIdx.x;
  const int lane = tid & 63, wave = tid >> 6;
  const int p = lane & 15, ql = lane >> 4;
  const int wm = wave >> 2, wn = wave & 3;

  const int gx = gridDim.x, nwg = gx * gridDim.y;
  const int bid = blockIdx.y * gx + blockIdx.x;
  const int q8 = nwg >> 3, r8 = nwg & 7;
  const int xcd = bid & 7, lxi = bid >> 3;
  const int swz = (xcd < r8 ? xcd * (q8 + 1) : r8 * (q8 + 1) + (xcd - r8) * q8) + lxi;
  const size_t row_blk = (size_t)(swz / gx) * 256;
  const size_t col_blk = (size_t)(swz % gx) * 256;

  int a_off[8], b_off[4];
#pragma unroll
  for (int m = 0; m < 8; ++m) {
    int r = wm * 128 + m * 16 + p;
    a_off[m] = r * 64 + ((ql ^ ((r >> 1) & 3)) << 4);
  }
#pragma unroll
  for (int n = 0; n < 4; ++n) {
    int r = wn * 64 + n * 16 + p;
    b_off[n] = r * 64 + ((ql ^ ((r >> 1) & 3)) << 4);
  }

  const int idx0 = tid, idx1 = tid + 512;
  const int sr0 = idx0 >> 2, sq0 = (idx0 & 3) ^ ((sr0 >> 1) & 3);
  const int sr1 = idx1 >> 2, sq1 = (idx1 & 3) ^ ((sr1 >> 1) & 3);

  auto stage = [&](int buf, int h, int kt) {
    const int lk = kt * 64;
    const int ak = ((lk >= 2048) ? 1024 : 0) + (lk & 1023) + h * 32;
    const int bk = ((lk >= 1024 && lk < 2048) ? 1024 : 0) + (lk & 1023) + h * 32;
    char* pa = lds + buf * 65536 + h * 16384;
    char* pb = pa + 32768;
    const __half* ga0 = A + (row_blk + sr0) * (size_t)KP + ak + sq0 * 8;
    const __half* ga1 = A + (row_blk + sr1) * (size_t)KP + ak + sq1 * 8;
    const __half* gb0 = B + (col_blk + sr0) * (size_t)KP + bk + sq0 * 8;
    const __half* gb1 = B + (col_blk + sr1) * (size_t)KP + bk + sq1 * 8;
    __builtin_amdgcn_global_load_lds((__attribute__((address_space(1))) void*)ga0,
        (__attribute__((address_space(3))) void*)(pa + idx0 * 16), 16, 0, 0);
    __builtin_amdgcn_global_load_lds((__attribute__((address_space(1))) void*)ga1,
        (__attribute__((address_space(3))) void*)(pa + idx1 * 16), 16, 0, 0);
    __builtin_amdgcn_global_load_lds((__attribute__((address_space(1))) void*)gb0,
        (__attribute__((address_space(3))) void*)(pb + idx0 * 16), 16, 0, 0);
    __builtin_amdgcn_global_load_lds((__attribute__((address_space(1))) void*)gb1,
        (__attribute__((address_space(3))) void*)(pb + idx1 * 16), 16, 0, 0);
  };

  stage(0, 0, 0);
  stage(0, 1, 0);
  asm volatile("s_waitcnt vmcnt(0)" ::: "memory");
  __builtin_amdgcn_s_barrier();

  f32x4 acc[8][4] = {};

  for (int t = 0; t < NT; ++t) {
    const int bufp = t & 1;
    const int ts = (t + 1 < NT) ? t + 1 : NT - 1;
#pragma unroll
    for (int h = 0; h < 2; ++h) {
      const char* pA = lds + bufp * 65536 + h * 16384;
      const char* pB = pA + 32768;
      f16x8 af[8], bfr[4];
#pragma unroll
      for (int m = 0; m < 8; ++m) af[m] = *(const f16x8*)(pA + a_off[m]);
#pragma unroll
      for (int n = 0; n < 4; ++n) bfr[n] = *(const f16x8*)(pB + b_off[n]);
      stage(bufp ^ 1, h, ts);
      __builtin_amdgcn_sched_barrier(0);
      __builtin_amdgcn_s_barrier();
      __builtin_amdgcn_sched_barrier(0);
      __builtin_amdgcn_s_setprio(1);
#pragma unroll
      for (int m = 0; m < 8; ++m)
#pragma unroll
        for (int n = 0; n < 4; ++n)
          acc[m][n] = __builtin_amdgcn_mfma_f32_16x16x32_f16(af[m], bfr[n], acc[m][n], 0, 0, 0);
      __builtin_amdgcn_s_setprio(0);
      asm volatile("s_waitcnt vmcnt(4)" ::: "memory");
      __builtin_amdgcn_sched_barrier(0);
      __builtin_amdgcn_s_barrier();
      __builtin_amdgcn_sched_barrier(0);
    }
  }

  const float unscale = 1.f / 16384.f;
#pragma unroll
  for (int n = 0; n < 4; ++n) {
    const size_t col = col_blk + wn * 64 + n * 16 + p;
    const float bv = bias[col];
#pragma unroll
    for (int m = 0; m < 8; ++m) {
      const size_t row0 = row_blk + wm * 128 + m * 16 + ql * 4;
#pragma unroll
      for (int j = 0; j < 4; ++j) {
        float v = acc[m][n][j] * unscale + bv;
        const size_t o = (row0 + j) * (size_t)KP + col;
        float r = fmaxf(v, 0.f) * 64.f;
        __half hh = __float2half(r);
        Co[o] = hh;
        Co[o + 1024] = __float2half(r - __half2float(hh));
      }
    }
  }
}

// ---- K3: soft GEMM (both 256-col halves sequentially) + fused PWL epilogue ---
__global__ __launch_bounds__(512, 2)
void g3softepi(const __half* __restrict__ A, const __half* __restrict__ B,
               const float* __restrict__ b3, const float* __restrict__ y,
               float* __restrict__ out, int row0) {
  __shared__ char lds[131072 + 1024];
  float* qs = (float*)lds;                      // [64][256] f32, post-K-loop only
  float* prod_lds = (float*)(lds + 131072);     // [256] per-row cb=0 partial prod
  const int tid = threadIdx.x;
  const int lane = tid & 63, wave = tid >> 6;
  const int p = lane & 15, ql = lane >> 4;
  const int wm = wave >> 2, wn = wave & 3;

  // XCD-bijective swizzle over 1-D grid
  const int nwg = gridDim.x, bid = blockIdx.x;
  const int q8 = nwg >> 3, r8 = nwg & 7;
  const int xcd = bid & 7, lxi = bid >> 3;
  const int swz = (xcd < r8 ? xcd * (q8 + 1) : r8 * (q8 + 1) + (xcd - r8) * q8) + lxi;
  const size_t row_blk = (size_t)swz * 256;

  int a_off[8], b_off[4];
#pragma unroll
  for (int m = 0; m < 8; ++m) {
    int r = wm * 128 + m * 16 + p;
    a_off[m] = r * 64 + ((ql ^ ((r >> 1) & 3)) << 4);
  }
#pragma unroll
  for (int n = 0; n < 4; ++n) {
    int r = wn * 64 + n * 16 + p;
    b_off[n] = r * 64 + ((ql ^ ((r >> 1) & 3)) << 4);
  }

  const int idx0 = tid, idx1 = tid + 512;
  const int sr0 = idx0 >> 2, sq0 = (idx0 & 3) ^ ((sr0 >> 1) & 3);
  const int sr1 = idx1 >> 2, sq1 = (idx1 & 3) ^ ((sr1 >> 1) & 3);

  const float unscale = 1.f / 16384.f;

  for (int cb = 0; cb < 2; ++cb) {
    const int col_blk = cb * 256;

    auto stage = [&](int buf, int h, int kt) {
      const int lk = kt * 64;
      const int ak = ((lk >= 2048) ? 1024 : 0) + (lk & 1023) + h * 32;
      const int bk = ((lk >= 1024 && lk < 2048) ? 1024 : 0) + (lk & 1023) + h * 32;
      char* pa = lds + buf * 65536 + h * 16384;
      char* pb = pa + 32768;
      const __half* ga0 = A + (row_blk + sr0) * (size_t)KP + ak + sq0 * 8;
      const __half* ga1 = A + (row_blk + sr1) * (size_t)KP + ak + sq1 * 8;
      const __half* gb0 = B + (col_blk + sr0) * (size_t)KP + bk + sq0 * 8;
      const __half* gb1 = B + (col_blk + sr1) * (size_t)KP + bk + sq1 * 8;
      __builtin_amdgcn_global_load_lds((__attribute__((address_space(1))) void*)ga0,
          (__attribute__((address_space(3))) void*)(pa + idx0 * 16), 16, 0, 0);
      __builtin_amdgcn_global_load_lds((__attribute__((address_space(1))) void*)ga1,
          (__attribute__((address_space(3))) void*)(pa + idx1 * 16), 16, 0, 0);
      __builtin_amdgcn_global_load_lds((__attribute__((address_space(1))) void*)gb0,
          (__attribute__((address_space(3))) void*)(pb + idx0 * 16), 16, 0, 0);
      __builtin_amdgcn_global_load_lds((__attribute__((address_space(1))) void*)gb1,
          (__attribute__((address_space(3))) void*)(pb + idx1 * 16), 16, 0, 0);
    };

    stage(0, 0, 0);
    stage(0, 1, 0);
    asm volatile("s_waitcnt vmcnt(0)" ::: "memory");
    __builtin_amdgcn_s_barrier();

    f32x4 acc[8][4] = {};

    for (int t = 0; t < NT; ++t) {
      const int bufp = t & 1;
      const int ts = (t + 1 < NT) ? t + 1 : NT - 1;
#pragma unroll
      for (int h = 0; h < 2; ++h) {
        const char* pA = lds + bufp * 65536 + h * 16384;
        const char* pB = pA + 32768;
        f16x8 af[8], bfr[4];
#pragma unroll
        for (int m = 0; m < 8; ++m) af[m] = *(const f16x8*)(pA + a_off[m]);
#pragma unroll
        for (int n = 0; n < 4; ++n) bfr[n] = *(const f16x8*)(pB + b_off[n]);
        stage(bufp ^ 1, h, ts);
        __builtin_amdgcn_sched_barrier(0);
        __builtin_amdgcn_s_barrier();
        __builtin_amdgcn_sched_barrier(0);
        __builtin_amdgcn_s_setprio(1);
#pragma unroll
        for (int m = 0; m < 8; ++m)
#pragma unroll
          for (int n = 0; n < 4; ++n)
            acc[m][n] = __builtin_amdgcn_mfma_f32_16x16x32_f16(af[m], bfr[n], acc[m][n], 0, 0, 0);
        __builtin_amdgcn_s_setprio(0);
        asm volatile("s_waitcnt vmcnt(4)" ::: "memory");
        __builtin_amdgcn_sched_barrier(0);
        __builtin_amdgcn_s_barrier();
        __builtin_amdgcn_sched_barrier(0);
      }
    }

    // drain dummy prefetches before reusing LDS as q-scan scratch (race fix)
    asm volatile("s_waitcnt vmcnt(0)" ::: "memory");
    __syncthreads();

    // 4 passes of 64 rows: stage softplus'd q to LDS, scan, write out
    for (int pass = 0; pass < 4; ++pass) {
      if (wm == (pass >> 1)) {
#pragma unroll
        for (int mm = 0; mm < 4; ++mm) {
          const int m = (pass & 1) * 4 + mm;
#pragma unroll
          for (int n = 0; n < 4; ++n) {
            const int colq = wn * 64 + n * 16 + p;
            const float bv = b3[col_blk + colq];
#pragma unroll
            for (int j = 0; j < 4; ++j) {
              float v = acc[m][n][j] * unscale + bv;
              float sp = fmaxf(v, 0.f) + log1pf(expf(-fabsf(v)));
              const int rloc = m * 16 + ql * 4 + j - (pass & 1) * 64;
              qs[rloc * 256 + colq] = sp + 1e-6f;
            }
          }
        }
      }
      __syncthreads();

      for (int i = 0; i < 8; ++i) {
        const int rloc = wave * 8 + i;
        const size_t rg = row0 + row_blk + pass * 64 + rloc;
        const float* yr = y + rg * 17;
        float* orow = out + rg * 17;
        float prod = 1.f;
#pragma unroll
        for (int tl = 0; tl < 4; ++tl) {
          const int t = cb * 4 + tl;
          const float qv = qs[rloc * 256 + tl * 64 + lane];
          float s = qv;
#pragma unroll
          for (int d = 1; d < 64; d <<= 1) {
            float u = __shfl_up(s, d);
            if (lane >= d) s += u;
          }
          const float total = __shfl(s, 63);
          const float sn = s / total;
          const float dnorm = total * 0.015625f;
          const float slope_l = qv / dnorm;
          const float yb = yr[8 + t];
          const unsigned long long mb = __ballot(sn < yb);
          int bin = (int)__popcll(mb);
          bin = bin > 63 ? 63 : bin;
          const float off_g = __shfl(sn, bin > 0 ? bin - 1 : 0);
          const float off = (bin == 0) ? 0.f : off_g;
          const float sl = __shfl(slope_l, bin);
          const float xB = (yb - off) / sl + (float)bin * 0.015625f;
          if (lane == t) orow[8 + t] = xB;
          prod *= (1.f / sl);
        }
        if (cb == 0) {
          if (lane == 0) prod_lds[pass * 64 + rloc] = prod;
        } else {
          if (lane < 8) orow[lane] = yr[lane];
          if (lane == 8) orow[16] = yr[16] * prod_lds[pass * 64 + rloc] * prod;
        }
      }
      __syncthreads();
    }
  }
}

// ---- launch ------------------------------------------------------------------
extern "C" void kernel_launch(void* const* d_in, const int* in_sizes, int n_in,
                              void* d_out, int out_size, void* d_ws, size_t ws_size,
                              hipStream_t stream) {
  const float* y  = (const float*)d_in[0];
  const float* w1 = (const float*)d_in[1];
  const float* b1 = (const float*)d_in[2];
  const float* w2 = (const float*)d_in[3];
  const float* b2 = (const float*)d_in[4];
  const float* w3 = (const float*)d_in[5];
  const float* b3 = (const float*)d_in[6];
  float* out = (float*)d_out;
  const long Btot = in_sizes[0] / 17;

  char* ws = (char*)d_ws;
  __half* w2t = (__half*)ws;                      // 4 MB  [1024][2048] hi|lo
  __half* w3t = (__half*)(ws + (4u << 20));       // 2 MB  [512][2048]  hi|lo
  const size_t fixed = (size_t)6 << 20;

  size_t avail = ws_size > fixed ? ws_size - fixed : 0;
  long maxrows = (long)(avail / 8192);
  long chunk = Btot < maxrows ? Btot : maxrows;
  chunk &= ~255L;
  if (chunk < 256) chunk = 256;

  __half* h1buf = (__half*)(ws + fixed);
  __half* h2buf = (__half*)(ws + fixed + (size_t)chunk * 4096);

  tconv_both<<<dim3(32, 32, 2), dim3(32, 8), 0, stream>>>(w2, w2t, w3, w3t);

  for (long row0 = 0; row0 < Btot; row0 += chunk) {
    const int nr = (int)((Btot - row0 < chunk) ? (Btot - row0) : chunk);
    h1k<<<(nr + 1) / 2, 256, 0, stream>>>(y, w1, b1, h1buf, (int)row0, nr);
    g2relu<<<dim3(HID / 256, nr / 256), 512, 0, stream>>>(h1buf, w2t, b2, h2buf);
    g3softepi<<<nr / 256, 512, 0, stream>>>(h2buf, w3t, b3, y, out, (int)row0);
  }
}

// Round 7
// 1082.217 us; speedup vs baseline: 1.9058x; 1.9058x over previous
//
#include <hip/hip_runtime.h>
#include <hip/hip_fp16.h>

#define HID 1024
#define QCOLS 512
#define KP 2048   // physical K per operand: [hi(1024) | lo(1024)]
#define NT 48     // logical K' = 3072 = 48 tiles of 64

typedef _Float16 f16x8 __attribute__((ext_vector_type(8)));
typedef float f32x4 __attribute__((ext_vector_type(4)));

// ---- K0: transpose+convert+split both weights in one dispatch ----------------
__global__ void tconv_both(const float* __restrict__ w2, __half* __restrict__ w2t,
                           const float* __restrict__ w3, __half* __restrict__ w3t) {
  __shared__ float tile[32][33];
  const int z = blockIdx.z;
  const int N = z ? QCOLS : HID;
  if (blockIdx.x * 32 >= N) return;
  const float* src = z ? w3 : w2;
  __half* dst = z ? w3t : w2t;
  int n0 = blockIdx.x * 32, k0 = blockIdx.y * 32;
  int tx = threadIdx.x, ty = threadIdx.y;
  for (int i = ty; i < 32; i += 8)
    tile[i][tx] = src[(size_t)(k0 + i) * N + n0 + tx];
  __syncthreads();
  for (int i = ty; i < 32; i += 8) {
    float v = tile[tx][i] * 256.f;
    __half h = __float2half(v);
    size_t o = (size_t)(n0 + i) * KP + k0 + tx;
    dst[o] = h;
    dst[o + 1024] = __float2half(v - __half2float(h));
  }
}

// ---- K1: h1 = relu(yA @ w1 + b1) fp32, split to [hi|lo] f16 (x64) ------------
__global__ __launch_bounds__(256)
void h1k(const float* __restrict__ y, const float* __restrict__ w1,
         const float* __restrict__ b1, __half* __restrict__ h1,
         int row0, int nrows) {
  const int t = threadIdx.x & 127;
  const int rl = threadIdx.x >> 7;
  const long r = (long)blockIdx.x * 2 + rl;
  if (r >= nrows) return;
  const float* yr = y + (size_t)(row0 + r) * 17;
  float yv[8];
#pragma unroll
  for (int k = 0; k < 8; ++k) yv[k] = yr[k];
  const int c0 = t * 8;
  f32x4 a0 = *(const f32x4*)(b1 + c0);
  f32x4 a1 = *(const f32x4*)(b1 + c0 + 4);
#pragma unroll
  for (int k = 0; k < 8; ++k) {
    const f32x4 w0 = *(const f32x4*)(w1 + k * HID + c0);
    const f32x4 w1v = *(const f32x4*)(w1 + k * HID + c0 + 4);
#pragma unroll
    for (int j = 0; j < 4; ++j) {
      a0[j] = fmaf(yv[k], w0[j], a0[j]);
      a1[j] = fmaf(yv[k], w1v[j], a1[j]);
    }
  }
  f16x8 hi, lo;
#pragma unroll
  for (int j = 0; j < 8; ++j) {
    float v = fmaxf(j < 4 ? a0[j] : a1[j - 4], 0.f) * 64.f;
    _Float16 h = (_Float16)v;
    hi[j] = h;
    lo[j] = (_Float16)(v - (float)h);
  }
  *(f16x8*)(h1 + (size_t)r * KP + c0) = hi;
  *(f16x8*)(h1 + (size_t)r * KP + c0 + 1024) = lo;
}

// ---- 256x256 deep-pipelined split-f16 GEMM core ------------------------------
// ACT 0: relu -> split f16 [hi|lo] (x64), ldc=KP. ACT 1: softplus -> f32, ldc=QCOLS.
template <int ACT>
__device__ __forceinline__
void gemm8p_body(const __half* __restrict__ A, const __half* __restrict__ B,
                 const float* __restrict__ bias, __half* __restrict__ Co,
                 float* __restrict__ Cf, int ldc) {
  __shared__ char lds[131072];
  const int tid = threadIdx.x;
  const int lane = tid & 63, wave = tid >> 6;
  const int p = lane & 15, ql = lane >> 4;
  const int wm = wave >> 2, wn = wave & 3;

  // XCD-bijective block swizzle (m204)
  const int gx = gridDim.x, nwg = gx * gridDim.y;
  const int bid = blockIdx.y * gx + blockIdx.x;
  const int q8 = nwg >> 3, r8 = nwg & 7;
  const int xcd = bid & 7, lxi = bid >> 3;
  const int swz = (xcd < r8 ? xcd * (q8 + 1) : r8 * (q8 + 1) + (xcd - r8) * q8) + lxi;
  const size_t row_blk = (size_t)(swz / gx) * 256;
  const size_t col_blk = (size_t)(swz % gx) * 256;

  int a_off[8], b_off[4];
#pragma unroll
  for (int m = 0; m < 8; ++m) {
    int r = wm * 128 + m * 16 + p;
    a_off[m] = r * 64 + ((ql ^ ((r >> 1) & 3)) << 4);
  }
#pragma unroll
  for (int n = 0; n < 4; ++n) {
    int r = wn * 64 + n * 16 + p;
    b_off[n] = r * 64 + ((ql ^ ((r >> 1) & 3)) << 4);
  }

  const int idx0 = tid, idx1 = tid + 512;
  const int sr0 = idx0 >> 2, sq0 = (idx0 & 3) ^ ((sr0 >> 1) & 3);
  const int sr1 = idx1 >> 2, sq1 = (idx1 & 3) ^ ((sr1 >> 1) & 3);

  auto stage = [&](int buf, int h, int kt) {
    const int lk = kt * 64;
    const int ak = ((lk >= 2048) ? 1024 : 0) + (lk & 1023) + h * 32;
    const int bk = ((lk >= 1024 && lk < 2048) ? 1024 : 0) + (lk & 1023) + h * 32;
    char* pa = lds + buf * 65536 + h * 16384;
    char* pb = pa + 32768;
    const __half* ga0 = A + (row_blk + sr0) * (size_t)KP + ak + sq0 * 8;
    const __half* ga1 = A + (row_blk + sr1) * (size_t)KP + ak + sq1 * 8;
    const __half* gb0 = B + (col_blk + sr0) * (size_t)KP + bk + sq0 * 8;
    const __half* gb1 = B + (col_blk + sr1) * (size_t)KP + bk + sq1 * 8;
    __builtin_amdgcn_global_load_lds((__attribute__((address_space(1))) void*)ga0,
        (__attribute__((address_space(3))) void*)(pa + idx0 * 16), 16, 0, 0);
    __builtin_amdgcn_global_load_lds((__attribute__((address_space(1))) void*)ga1,
        (__attribute__((address_space(3))) void*)(pa + idx1 * 16), 16, 0, 0);
    __builtin_amdgcn_global_load_lds((__attribute__((address_space(1))) void*)gb0,
        (__attribute__((address_space(3))) void*)(pb + idx0 * 16), 16, 0, 0);
    __builtin_amdgcn_global_load_lds((__attribute__((address_space(1))) void*)gb1,
        (__attribute__((address_space(3))) void*)(pb + idx1 * 16), 16, 0, 0);
  };

  stage(0, 0, 0);
  stage(0, 1, 0);
  asm volatile("s_waitcnt vmcnt(0)" ::: "memory");
  __builtin_amdgcn_s_barrier();

  f32x4 acc[8][4] = {};

  for (int t = 0; t < NT; ++t) {
    const int bufp = t & 1;
    const int ts = (t + 1 < NT) ? t + 1 : NT - 1;
#pragma unroll
    for (int h = 0; h < 2; ++h) {
      const char* pA = lds + bufp * 65536 + h * 16384;
      const char* pB = pA + 32768;
      f16x8 af[8], bfr[4];
#pragma unroll
      for (int m = 0; m < 8; ++m) af[m] = *(const f16x8*)(pA + a_off[m]);
#pragma unroll
      for (int n = 0; n < 4; ++n) bfr[n] = *(const f16x8*)(pB + b_off[n]);
      stage(bufp ^ 1, h, ts);
      __builtin_amdgcn_sched_barrier(0);
      __builtin_amdgcn_s_barrier();
      __builtin_amdgcn_sched_barrier(0);
      __builtin_amdgcn_s_setprio(1);
#pragma unroll
      for (int m = 0; m < 8; ++m)
#pragma unroll
        for (int n = 0; n < 4; ++n)
          acc[m][n] = __builtin_amdgcn_mfma_f32_16x16x32_f16(af[m], bfr[n], acc[m][n], 0, 0, 0);
      __builtin_amdgcn_s_setprio(0);
      asm volatile("s_waitcnt vmcnt(4)" ::: "memory");
      __builtin_amdgcn_sched_barrier(0);
      __builtin_amdgcn_s_barrier();
      __builtin_amdgcn_sched_barrier(0);
    }
  }

  const float unscale = 1.f / 16384.f;
#pragma unroll
  for (int n = 0; n < 4; ++n) {
    const size_t col = col_blk + wn * 64 + n * 16 + p;
    const float bv = bias[col];
#pragma unroll
    for (int m = 0; m < 8; ++m) {
      const size_t row0 = row_blk + wm * 128 + m * 16 + ql * 4;
#pragma unroll
      for (int j = 0; j < 4; ++j) {
        float v = acc[m][n][j] * unscale + bv;
        const size_t o = (row0 + j) * (size_t)ldc + col;
        if constexpr (ACT == 0) {
          float r = fmaxf(v, 0.f) * 64.f;
          __half hh = __float2half(r);
          Co[o] = hh;
          Co[o + 1024] = __float2half(r - __half2float(hh));
        } else {
          float sp = fmaxf(v, 0.f) + log1pf(expf(-fabsf(v)));  // stable softplus
          Cf[o] = sp + 1e-6f;
        }
      }
    }
  }
}

__global__ __launch_bounds__(512, 2)
void g2relu(const __half* __restrict__ A, const __half* __restrict__ B,
            const float* __restrict__ bias, __half* __restrict__ Co) {
  gemm8p_body<0>(A, B, bias, Co, nullptr, KP);
}

__global__ __launch_bounds__(512, 2)
void g3soft(const __half* __restrict__ A, const __half* __restrict__ B,
            const float* __restrict__ bias, float* __restrict__ Cf) {
  gemm8p_body<1>(A, B, bias, nullptr, Cf, QCOLS);
}

// ---- K4: per-row piecewise-linear inverse + jacobian (np-order-matched) ------
__global__ __launch_bounds__(256)
void pwl_epi(const float* __restrict__ y, const float* __restrict__ q,
             float* __restrict__ out, int row0, int nrows) {
  const int wave = threadIdx.x >> 6, lane = threadIdx.x & 63;
  const int r = blockIdx.x * 4 + wave;
  if (r >= nrows) return;
  const float* yr = y + (size_t)(row0 + r) * 17;
  float* orow = out + (size_t)(row0 + r) * 17;
  const float* qr = q + (size_t)r * QCOLS;
  float prod_inv = 1.f;
#pragma unroll
  for (int t = 0; t < 8; ++t) {
    const float qv = qr[t * 64 + lane];
    float s = qv;
#pragma unroll
    for (int d = 1; d < 64; d <<= 1) {
      float u = __shfl_up(s, d);
      if (lane >= d) s += u;
    }
    const float total = __shfl(s, 63);
    const float sn = s / total;
    const float dnorm = total * 0.015625f;
    const float slope_l = qv / dnorm;
    const float yb = yr[8 + t];
    const unsigned long long m = __ballot(sn < yb);
    int bin = (int)__popcll(m);
    bin = bin > 63 ? 63 : bin;
    const float off_g = __shfl(sn, bin > 0 ? bin - 1 : 0);
    const float off = (bin == 0) ? 0.f : off_g;
    const float sl = __shfl(slope_l, bin);
    const float xB = (yb - off) / sl + (float)bin * 0.015625f;
    if (lane == t) orow[8 + t] = xB;
    prod_inv *= (1.f / sl);
  }
  if (lane < 8) orow[lane] = yr[lane];
  if (lane == 8) orow[16] = yr[16] * prod_inv;
}

// ---- launch ------------------------------------------------------------------
extern "C" void kernel_launch(void* const* d_in, const int* in_sizes, int n_in,
                              void* d_out, int out_size, void* d_ws, size_t ws_size,
                              hipStream_t stream) {
  const float* y  = (const float*)d_in[0];
  const float* w1 = (const float*)d_in[1];
  const float* b1 = (const float*)d_in[2];
  const float* w2 = (const float*)d_in[3];
  const float* b2 = (const float*)d_in[4];
  const float* w3 = (const float*)d_in[5];
  const float* b3 = (const float*)d_in[6];
  float* out = (float*)d_out;
  const long Btot = in_sizes[0] / 17;

  char* ws = (char*)d_ws;
  __half* w2t = (__half*)ws;                      // 4 MB  [1024][2048] hi|lo
  __half* w3t = (__half*)(ws + (4u << 20));       // 2 MB  [512][2048]  hi|lo
  const size_t fixed = (size_t)6 << 20;

  // Grid-aligned power-of-two chunking: largest 2^k rows that fit ws at
  // 8 KB/row (h1 split 4 KB + h2 split 4 KB; q f32 aliases h1's slot).
  // Keeps every GEMM grid a multiple of 128 blocks (full CU rounds) and
  // keeps h1/h2 L3-resident between producer and consumer.
  const size_t avail = ws_size > fixed ? ws_size - fixed : 0;
  long maxrows = (long)(avail / 8192);
  long chunk = 256;
  for (long c = 65536; c >= 256; c >>= 1) {
    if (c <= maxrows && c <= Btot) { chunk = c; break; }
  }

  __half* h1buf = (__half*)(ws + fixed);
  __half* h2buf = (__half*)(ws + fixed + (size_t)chunk * 4096);
  float* qbuf = (float*)h1buf;  // h1 dead once g2relu finishes

  tconv_both<<<dim3(32, 32, 2), dim3(32, 8), 0, stream>>>(w2, w2t, w3, w3t);

  for (long row0 = 0; row0 < Btot; row0 += chunk) {
    const int nr = (int)((Btot - row0 < chunk) ? (Btot - row0) : chunk);
    h1k<<<(nr + 1) / 2, 256, 0, stream>>>(y, w1, b1, h1buf, (int)row0, nr);
    g2relu<<<dim3(HID / 256, nr / 256), 512, 0, stream>>>(h1buf, w2t, b2, h2buf);
    g3soft<<<dim3(QCOLS / 256, nr / 256), 512, 0, stream>>>(h2buf, w3t, b3, qbuf);
    pwl_epi<<<(nr + 3) / 4, 256, 0, stream>>>(y, qbuf, out, (int)row0, nr);
  }
}

// Round 8
// 913.426 us; speedup vs baseline: 2.2580x; 1.1848x over previous
//
#include <hip/hip_runtime.h>
#include <hip/hip_fp16.h>

#define HID 1024
#define QCOLS 512
#define KP 2048   // physical K per operand: [hi(1024) | lo(1024)]
#define NT 48     // logical K' = 3072 = 48 tiles of 64

typedef _Float16 f16x8 __attribute__((ext_vector_type(8)));
typedef float f32x4 __attribute__((ext_vector_type(4)));

// ---- K0: transpose+convert+split both weights in one dispatch ----------------
__global__ void tconv_both(const float* __restrict__ w2, __half* __restrict__ w2t,
                           const float* __restrict__ w3, __half* __restrict__ w3t) {
  __shared__ float tile[32][33];
  const int z = blockIdx.z;
  const int N = z ? QCOLS : HID;
  if (blockIdx.x * 32 >= N) return;
  const float* src = z ? w3 : w2;
  __half* dst = z ? w3t : w2t;
  int n0 = blockIdx.x * 32, k0 = blockIdx.y * 32;
  int tx = threadIdx.x, ty = threadIdx.y;
  for (int i = ty; i < 32; i += 8)
    tile[i][tx] = src[(size_t)(k0 + i) * N + n0 + tx];
  __syncthreads();
  for (int i = ty; i < 32; i += 8) {
    float v = tile[tx][i] * 256.f;
    __half h = __float2half(v);
    size_t o = (size_t)(n0 + i) * KP + k0 + tx;
    dst[o] = h;
    dst[o + 1024] = __float2half(v - __half2float(h));
  }
}

// ---- K1: h1 = relu(yA @ w1 + b1) fp32, split to [hi|lo] f16 (x64) ------------
__global__ __launch_bounds__(256)
void h1k(const float* __restrict__ y, const float* __restrict__ w1,
         const float* __restrict__ b1, __half* __restrict__ h1,
         int row0, int nrows) {
  const int t = threadIdx.x & 127;
  const int rl = threadIdx.x >> 7;
  const long r = (long)blockIdx.x * 2 + rl;
  if (r >= nrows) return;
  const float* yr = y + (size_t)(row0 + r) * 17;
  float yv[8];
#pragma unroll
  for (int k = 0; k < 8; ++k) yv[k] = yr[k];
  const int c0 = t * 8;
  f32x4 a0 = *(const f32x4*)(b1 + c0);
  f32x4 a1 = *(const f32x4*)(b1 + c0 + 4);
#pragma unroll
  for (int k = 0; k < 8; ++k) {
    const f32x4 w0 = *(const f32x4*)(w1 + k * HID + c0);
    const f32x4 w1v = *(const f32x4*)(w1 + k * HID + c0 + 4);
#pragma unroll
    for (int j = 0; j < 4; ++j) {
      a0[j] = fmaf(yv[k], w0[j], a0[j]);
      a1[j] = fmaf(yv[k], w1v[j], a1[j]);
    }
  }
  f16x8 hi, lo;
#pragma unroll
  for (int j = 0; j < 8; ++j) {
    float v = fmaxf(j < 4 ? a0[j] : a1[j - 4], 0.f) * 64.f;
    _Float16 h = (_Float16)v;
    hi[j] = h;
    lo[j] = (_Float16)(v - (float)h);
  }
  *(f16x8*)(h1 + (size_t)r * KP + c0) = hi;
  *(f16x8*)(h1 + (size_t)r * KP + c0 + 1024) = lo;
}

// ---- 256xBN split-f16 GEMM with 4-slot ring (3 half-stages in flight) --------
// ACT 0: relu -> split f16 [hi|lo] (x64). ACT 1: softplus -> f32.
// Ring slot = [A 16KB | B BN*64B]; stage slot p+3 during phase p; vmcnt(2*LPS).
template <int ACT, int BN>
__device__ __forceinline__
void gemm_ring_body(const __half* __restrict__ A, const __half* __restrict__ Bt,
                    const float* __restrict__ bias, __half* __restrict__ Co,
                    float* __restrict__ Cf, int ldc) {
  constexpr int NFRAG = BN / 64;          // per-wave 16-col frags (2 or 4)
  constexpr int BNB = BN * 64;            // B plane bytes
  constexpr int SLOT = 16384 + BNB;       // ring slot bytes
  constexpr int LPS = 2 + BN / 128;       // gloads per thread per stage (3 or 4)
  __shared__ char lds[4 * SLOT];
  const int tid = threadIdx.x;
  const int lane = tid & 63, wave = tid >> 6;
  const int p = lane & 15, ql = lane >> 4;
  const int wm = wave >> 2, wn = wave & 3;

  // XCD-bijective block swizzle (m204)
  const int gx = gridDim.x, nwg = gx * gridDim.y;
  const int bid = blockIdx.y * gx + blockIdx.x;
  const int q8 = nwg >> 3, r8 = nwg & 7;
  const int xcd = bid & 7, lxi = bid >> 3;
  const int swz = (xcd < r8 ? xcd * (q8 + 1) : r8 * (q8 + 1) + (xcd - r8) * q8) + lxi;
  const size_t row_blk = (size_t)(swz / gx) * 256;
  const size_t col_blk = (size_t)(swz % gx) * BN;

  int a_off[8], b_off[NFRAG];
#pragma unroll
  for (int m = 0; m < 8; ++m) {
    int r = wm * 128 + m * 16 + p;
    a_off[m] = r * 64 + ((ql ^ ((r >> 1) & 3)) << 4);
  }
#pragma unroll
  for (int n = 0; n < NFRAG; ++n) {
    int r = wn * (BN / 4) + n * 16 + p;
    b_off[n] = r * 64 + ((ql ^ ((r >> 1) & 3)) << 4);
  }

  const int idx0 = tid, idx1 = tid + 512;
  const int sr0 = idx0 >> 2, sq0 = (idx0 & 3) ^ ((sr0 >> 1) & 3);
  const int sr1 = idx1 >> 2, sq1 = (idx1 & 3) ^ ((sr1 >> 1) & 3);

  auto gload = [&](const __half* g, char* l) {
    __builtin_amdgcn_global_load_lds((__attribute__((address_space(1))) void*)g,
        (__attribute__((address_space(3))) void*)l, 16, 0, 0);
  };

  // stage ring phase q: tile q>>1 (clamped), half q&1, into slot q&3
  auto stage = [&](int q) {
    int kt = q >> 1; if (kt > NT - 1) kt = NT - 1;
    const int h = q & 1;
    const int lk = kt * 64;
    const int ak = ((lk >= 2048) ? 1024 : 0) + (lk & 1023) + h * 32;
    const int bk = ((lk >= 1024 && lk < 2048) ? 1024 : 0) + (lk & 1023) + h * 32;
    char* base = lds + (q & 3) * SLOT;
    char* pb = base + 16384;
    gload(A + (row_blk + sr0) * (size_t)KP + ak + sq0 * 8, base + idx0 * 16);
    gload(A + (row_blk + sr1) * (size_t)KP + ak + sq1 * 8, base + idx1 * 16);
    gload(Bt + (col_blk + sr0) * (size_t)KP + bk + sq0 * 8, pb + idx0 * 16);
    if constexpr (BN == 256)
      gload(Bt + (col_blk + sr1) * (size_t)KP + bk + sq1 * 8, pb + idx1 * 16);
  };

  auto wait_ring = [&]() {  // keep 2 stages (2*LPS loads) in flight
    if constexpr (LPS == 4) asm volatile("s_waitcnt vmcnt(8)" ::: "memory");
    else                    asm volatile("s_waitcnt vmcnt(6)" ::: "memory");
  };

  // prologue: 3 half-stages in flight, oldest landed
  stage(0); stage(1); stage(2);
  wait_ring();
  __builtin_amdgcn_s_barrier();

  f32x4 acc[8][NFRAG] = {};

  for (int ph = 0; ph < NT * 2; ++ph) {
    const char* base = lds + (ph & 3) * SLOT;
    const char* pB = base + 16384;
    f16x8 af[8], bfr[NFRAG];
#pragma unroll
    for (int m = 0; m < 8; ++m) af[m] = *(const f16x8*)(base + a_off[m]);
#pragma unroll
    for (int n = 0; n < NFRAG; ++n) bfr[n] = *(const f16x8*)(pB + b_off[n]);
    stage(ph + 3);
    __builtin_amdgcn_sched_barrier(0);
    __builtin_amdgcn_s_barrier();
    __builtin_amdgcn_sched_barrier(0);
    __builtin_amdgcn_s_setprio(1);
#pragma unroll
    for (int m = 0; m < 8; ++m)
#pragma unroll
      for (int n = 0; n < NFRAG; ++n)
        acc[m][n] = __builtin_amdgcn_mfma_f32_16x16x32_f16(af[m], bfr[n], acc[m][n], 0, 0, 0);
    __builtin_amdgcn_s_setprio(0);
    wait_ring();
    __builtin_amdgcn_sched_barrier(0);
    __builtin_amdgcn_s_barrier();
    __builtin_amdgcn_sched_barrier(0);
  }

  const float unscale = 1.f / 16384.f;
#pragma unroll
  for (int n = 0; n < NFRAG; ++n) {
    const size_t col = col_blk + wn * (BN / 4) + n * 16 + p;
    const float bv = bias[col];
#pragma unroll
    for (int m = 0; m < 8; ++m) {
      const size_t row0 = row_blk + wm * 128 + m * 16 + ql * 4;
#pragma unroll
      for (int j = 0; j < 4; ++j) {
        float v = acc[m][n][j] * unscale + bv;
        const size_t o = (row0 + j) * (size_t)ldc + col;
        if constexpr (ACT == 0) {
          float r = fmaxf(v, 0.f) * 64.f;
          __half hh = __float2half(r);
          Co[o] = hh;
          Co[o + 1024] = __float2half(r - __half2float(hh));
        } else {
          float sp = fmaxf(v, 0.f) + log1pf(expf(-fabsf(v)));  // stable softplus
          Cf[o] = sp + 1e-6f;
        }
      }
    }
  }
}

__global__ __launch_bounds__(512, 2)
void g2relu(const __half* __restrict__ A, const __half* __restrict__ B,
            const float* __restrict__ bias, __half* __restrict__ Co) {
  gemm_ring_body<0, 256>(A, B, bias, Co, nullptr, KP);
}

__global__ __launch_bounds__(512, 2)
void g3soft(const __half* __restrict__ A, const __half* __restrict__ B,
            const float* __restrict__ bias, float* __restrict__ Cf) {
  gemm_ring_body<1, 128>(A, B, bias, nullptr, Cf, QCOLS);
}

// ---- K4: per-row piecewise-linear inverse + jacobian (np-order-matched) ------
__global__ __launch_bounds__(256)
void pwl_epi(const float* __restrict__ y, const float* __restrict__ q,
             float* __restrict__ out, int row0, int nrows) {
  const int wave = threadIdx.x >> 6, lane = threadIdx.x & 63;
  const int r = blockIdx.x * 4 + wave;
  if (r >= nrows) return;
  const float* yr = y + (size_t)(row0 + r) * 17;
  float* orow = out + (size_t)(row0 + r) * 17;
  const float* qr = q + (size_t)r * QCOLS;
  float prod_inv = 1.f;
#pragma unroll
  for (int t = 0; t < 8; ++t) {
    const float qv = qr[t * 64 + lane];
    float s = qv;
#pragma unroll
    for (int d = 1; d < 64; d <<= 1) {
      float u = __shfl_up(s, d);
      if (lane >= d) s += u;
    }
    const float total = __shfl(s, 63);
    const float sn = s / total;
    const float dnorm = total * 0.015625f;
    const float slope_l = qv / dnorm;
    const float yb = yr[8 + t];
    const unsigned long long m = __ballot(sn < yb);
    int bin = (int)__popcll(m);
    bin = bin > 63 ? 63 : bin;
    const float off_g = __shfl(sn, bin > 0 ? bin - 1 : 0);
    const float off = (bin == 0) ? 0.f : off_g;
    const float sl = __shfl(slope_l, bin);
    const float xB = (yb - off) / sl + (float)bin * 0.015625f;
    if (lane == t) orow[8 + t] = xB;
    prod_inv *= (1.f / sl);
  }
  if (lane < 8) orow[lane] = yr[lane];
  if (lane == 8) orow[16] = yr[16] * prod_inv;
}

// ---- launch ------------------------------------------------------------------
extern "C" void kernel_launch(void* const* d_in, const int* in_sizes, int n_in,
                              void* d_out, int out_size, void* d_ws, size_t ws_size,
                              hipStream_t stream) {
  const float* y  = (const float*)d_in[0];
  const float* w1 = (const float*)d_in[1];
  const float* b1 = (const float*)d_in[2];
  const float* w2 = (const float*)d_in[3];
  const float* b2 = (const float*)d_in[4];
  const float* w3 = (const float*)d_in[5];
  const float* b3 = (const float*)d_in[6];
  float* out = (float*)d_out;
  const long Btot = in_sizes[0] / 17;

  char* ws = (char*)d_ws;
  __half* w2t = (__half*)ws;                      // 4 MB  [1024][2048] hi|lo
  __half* w3t = (__half*)(ws + (4u << 20));       // 2 MB  [512][2048]  hi|lo
  const size_t fixed = (size_t)6 << 20;

  // Power-of-two chunks at 8 KB/row (h1 4 KB + h2 4 KB; q f32 aliases h1).
  const size_t avail = ws_size > fixed ? ws_size - fixed : 0;
  long maxrows = (long)(avail / 8192);
  long chunk = 256;
  for (long c = 65536; c >= 256; c >>= 1) {
    if (c <= maxrows && c <= Btot) { chunk = c; break; }
  }

  __half* h1buf = (__half*)(ws + fixed);
  __half* h2buf = (__half*)(ws + fixed + (size_t)chunk * 4096);
  float* qbuf = (float*)h1buf;  // h1 dead once g2relu finishes

  tconv_both<<<dim3(32, 32, 2), dim3(32, 8), 0, stream>>>(w2, w2t, w3, w3t);

  for (long row0 = 0; row0 < Btot; row0 += chunk) {
    const int nr = (int)((Btot - row0 < chunk) ? (Btot - row0) : chunk);
    h1k<<<(nr + 1) / 2, 256, 0, stream>>>(y, w1, b1, h1buf, (int)row0, nr);
    g2relu<<<dim3(HID / 256, nr / 256), 512, 0, stream>>>(h1buf, w2t, b2, h2buf);
    g3soft<<<dim3(QCOLS / 128, nr / 256), 512, 0, stream>>>(h2buf, w3t, b3, qbuf);
    pwl_epi<<<(nr + 3) / 4, 256, 0, stream>>>(y, qbuf, out, (int)row0, nr);
  }
}